// Round 3
// baseline (408.045 us; speedup 1.0000x reference)
//
#include <hip/hip_runtime.h>
#include <hip/hip_cooperative_groups.h>
#include <math.h>

namespace cg = cooperative_groups;

#define SQRTC  0.94868329805051381f       // sqrt(0.9)
#define MAXN   (0.996f/SQRTC)             // (1-PROJ_EPS)/sqrt(c)
#define OME_CLIP (1.0f - 0.996f*0.996f)   // 1 - c*maxnorm^2
#define TWO_OVER_SQRTC 2.1081851067789197f

typedef unsigned short u16;
typedef __attribute__((ext_vector_type(8))) short bf8;   // 8 bf16 (4 VGPRs)
typedef __attribute__((ext_vector_type(4))) float f4;    // MFMA C/D

__device__ __forceinline__ u16 f2bf(float f){
    union { float f; unsigned int i; } v; v.f = f;
    unsigned int x = v.i;
    unsigned int lsb = (x >> 16) & 1u;
    x += 0x7fffu + lsb;
    return (u16)(x >> 16);
}
__device__ __forceinline__ float bf2f(u16 u){
    union { unsigned int i; float f; } v; v.i = ((unsigned int)u) << 16; return v.f;
}

// async global->LDS, 16B per lane (dest = wave-uniform base + lane*16, linear)
__device__ __forceinline__ void gload16(void* lds, const void* g){
    __builtin_amdgcn_global_load_lds(
        (const __attribute__((address_space(1))) unsigned int*)g,
        (__attribute__((address_space(3))) unsigned int*)lds,
        16, 0, 0);
}

__device__ __forceinline__ float pdist_stable(float ome_x, float ome_y, float t){
    float u = 1.0f - ome_x, v = 1.0f - ome_y;   // c*x2, c*y2
    float den = fmaxf(1.0f - 1.8f*t + u*v, 1e-15f);
    float q = ome_x*ome_y/den;                   // = 1 - z^2
    q = fminf(fmaxf(q, 2.0e-7f), 1.0f);
    float z = sqrtf(fmaxf(1.0f - q, 0.0f));
    float at = 0.5f * logf((1.0f+z)*(1.0f+z)/q); // atanh(z)
    return TWO_OVER_SQRTC * at;
}

__device__ __forceinline__ void expmap_scale_ome(float sum, float* fout, float* omeout){
    float nraw = sqrtf(fmaxf(sum, 1e-30f));
    float n = fmaxf(nraw, 1e-15f);
    float sn = SQRTC*n;
    float th = tanhf(sn);
    float factor = th/sn;
    float gn = factor*nraw;
    if (gn > MAXN){ *fout = factor*(MAXN/gn); *omeout = OME_CLIP; }
    else { *fout = factor; *omeout = fmaxf((1.0f-th)*(1.0f+th), 1e-12f); }
}

// Single cooperative kernel: 256 blocks x 256 threads (1 block/CU guaranteed).
// P1 prep -> P2 conv+gemv -> P3 W_p+expmap -> P4 dots -> P5 final, grid.sync between.
__global__ __launch_bounds__(256, 1)
void k_mega(const float* __restrict__ summ, const float* __restrict__ cand,
            const float* __restrict__ text,
            const float* __restrict__ w1, const float* __restrict__ w2,
            const float* __restrict__ wp,
            const float* __restrict__ cb1, const float* __restrict__ cb2,
            const float* __restrict__ W_d, const float* __restrict__ W_s,
            const float* __restrict__ W_c,
            float* __restrict__ smax, float* __restrict__ cmax,
            u16* __restrict__ textb, u16* __restrict__ w1t,
            u16* __restrict__ w2t, u16* __restrict__ wpt,
            u16* __restrict__ gram, float* __restrict__ emb_all,
            float* __restrict__ ome_all, u16* __restrict__ emb_b,
            u16* __restrict__ dwe_b,
            float* __restrict__ doc_inter, float* __restrict__ sum_inter,
            float* __restrict__ cand_inter, float* __restrict__ out)
{
    __shared__ char smem[16384];
    cg::grid_group gg = cg::this_grid();
    const int bx0 = blockIdx.x;
    const int t = threadIdx.x;

    // ================= Phase 1: rowmax / text cvt / weight transposes =================
    for (int job = bx0; job < 2428; job += 256){
        if (job < 252){
            int row = job / 3, hc = job - row*3;
            int w = t >> 6, lane = t & 63;
            const float* in = (row < 4) ? (summ + (long long)row*128*768)
                                        : (cand + (long long)(row-4)*128*768);
            const float* p = in + (long long)(w*32)*768 + hc*256 + lane*4;
            float4 m = make_float4(-INFINITY,-INFINITY,-INFINITY,-INFINITY);
            #pragma unroll 8
            for (int l = 0; l < 32; l++){
                float4 v = *(const float4*)(p + (long long)l*768);
                m.x = fmaxf(m.x, v.x); m.y = fmaxf(m.y, v.y);
                m.z = fmaxf(m.z, v.z); m.w = fmaxf(m.w, v.w);
            }
            float4* sm4 = (float4*)smem;          // [4][64] float4
            sm4[w*64 + lane] = m; __syncthreads();
            if (t < 64){
                float4 a = sm4[t], b4 = sm4[64+t], c4 = sm4[128+t], d4 = sm4[192+t];
                float4 r;
                r.x = fmaxf(fmaxf(a.x,b4.x), fmaxf(c4.x,d4.x));
                r.y = fmaxf(fmaxf(a.y,b4.y), fmaxf(c4.y,d4.y));
                r.z = fmaxf(fmaxf(a.z,b4.z), fmaxf(c4.z,d4.z));
                r.w = fmaxf(fmaxf(a.w,b4.w), fmaxf(c4.w,d4.w));
                float* outp = (row < 4) ? (smax + row*768) : (cmax + (row-4)*768);
                *(float4*)(outp + hc*256 + t*4) = r;
            }
        } else if (job < 1020){
            int pb = job - 252;
            int base = pb*2048 + t*8;
            float4 a = *(const float4*)(text + base);
            float4 b = *(const float4*)(text + base + 4);
            *(ushort4*)(textb + base)     = make_ushort4(f2bf(a.x), f2bf(a.y), f2bf(a.z), f2bf(a.w));
            *(ushort4*)(textb + base + 4) = make_ushort4(f2bf(b.x), f2bf(b.y), f2bf(b.z), f2bf(b.w));
        } else {
            int j = job - 1020;
            const float* in; u16* outp; int K;
            if (j < 384){ in = w1; outp = w1t; K = 768; }
            else if (j < 1152){ j -= 384; in = w2; outp = w2t; K = 1536; }
            else { j -= 1152; in = wp; outp = wpt; K = 512; }
            const int N = 512, ntile = N/32;
            int k0 = (j/ntile)*32, n0 = (j - (j/ntile)*ntile)*32;
            int tx = t & 31, ty = t >> 5;
            float* shm = (float*)smem;            // 32x33 floats
            #pragma unroll
            for (int i = 0; i < 4; i++)
                shm[(ty*4+i)*33 + tx] = in[(long long)(k0 + ty*4 + i)*N + n0 + tx];
            __syncthreads();
            #pragma unroll
            for (int i = 0; i < 4; i++)
                outp[(long long)(n0 + ty*4 + i)*K + k0 + tx] = f2bf(shm[tx*33 + ty*4+i]);
        }
        __syncthreads();
    }
    __threadfence(); gg.sync();

    // ================= Phase 2: conv MFMA (512, parity-mixed) + emb_gemv (704) ======
    for (int jr = bx0; jr < 1216; jr += 256){
        int job = (jr >= 256 && jr < 512) ? (jr ^ 1) : jr;   // one K=768 + one K=1536 per block
        if (job < 512){
            u16* As = (u16*)smem;            // [64][64] u16, granule-XOR-swizzled
            u16* Bs = (u16*)(smem + 8192);   // [64][64] u16
            int xx = job & 63, yy = job >> 6;
            int jb = xx & 1;
            int m0 = (xx >> 1) * 64;
            int n0 = yy * 64;
            int K   = jb ? 1536 : 768;
            int M   = jb ? 2036 : 2040;
            int rpb = jb ? 509 : 510;
            int ob  = jb ? 510 : 0;
            const u16* Bt = jb ? w2t : w1t;
            const float* bias = jb ? cb2 : cb1;

            int r0 = t >> 3;                       // 0..31
            int co = (((t & 7) ^ (r0 & 7)) << 3);  // u16 offset within BK=64 window

            int gm0 = m0 + r0;      if (gm0 >= M) gm0 = M - 1;
            int gm1 = m0 + r0 + 32; if (gm1 >= M) gm1 = M - 1;
            int ab0 = gm0 / rpb, al0 = gm0 - ab0*rpb;
            int ab1 = gm1 / rpb, al1 = gm1 - ab1*rpb;
            const u16* a0 = textb + (long long)ab0*393216 + (long long)(al0+1)*768 + co;
            const u16* a1 = textb + (long long)ab1*393216 + (long long)(al1+1)*768 + co;
            const u16* bp0 = Bt + (long long)(n0 + r0)*K      + co;
            const u16* bp1 = Bt + (long long)(n0 + r0 + 32)*K + co;
            u16* lA0 = As + t*8;
            u16* lA1 = As + (256 + t)*8;
            u16* lB0 = Bs + t*8;
            u16* lB1 = Bs + (256 + t)*8;

            int lane = t & 63, wv = t >> 6;
            int fm = lane & 15, fq = lane >> 4;
            int arow = wv*16 + fm;
            int aswz = arow & 7, bswz = fm & 7;
            int aoff0 = arow*64 + ((fq     ^ aswz) << 3);
            int aoff1 = arow*64 + (((4+fq) ^ aswz) << 3);
            int boff0 = ((fq     ^ bswz) << 3);
            int boff1 = (((4+fq) ^ bswz) << 3);

            f4 acc0 = {0,0,0,0}, acc1 = {0,0,0,0}, acc2 = {0,0,0,0}, acc3 = {0,0,0,0};
            for (int k0 = 0; k0 < K; k0 += 64){
                gload16(lA0, a0 + k0);
                gload16(lA1, a1 + k0);
                gload16(lB0, bp0 + k0);
                gload16(lB1, bp1 + k0);
                __syncthreads();
                bf8 af0 = *(const bf8*)(As + aoff0);
                bf8 af1 = *(const bf8*)(As + aoff1);
                bf8 b00 = *(const bf8*)(Bs + (fm   )*64 + boff0);
                bf8 b10 = *(const bf8*)(Bs + (16+fm)*64 + boff0);
                bf8 b20 = *(const bf8*)(Bs + (32+fm)*64 + boff0);
                bf8 b30 = *(const bf8*)(Bs + (48+fm)*64 + boff0);
                bf8 b01 = *(const bf8*)(Bs + (fm   )*64 + boff1);
                bf8 b11 = *(const bf8*)(Bs + (16+fm)*64 + boff1);
                bf8 b21 = *(const bf8*)(Bs + (32+fm)*64 + boff1);
                bf8 b31 = *(const bf8*)(Bs + (48+fm)*64 + boff1);
                acc0 = __builtin_amdgcn_mfma_f32_16x16x32_bf16(af0, b00, acc0, 0, 0, 0);
                acc1 = __builtin_amdgcn_mfma_f32_16x16x32_bf16(af0, b10, acc1, 0, 0, 0);
                acc2 = __builtin_amdgcn_mfma_f32_16x16x32_bf16(af0, b20, acc2, 0, 0, 0);
                acc3 = __builtin_amdgcn_mfma_f32_16x16x32_bf16(af0, b30, acc3, 0, 0, 0);
                acc0 = __builtin_amdgcn_mfma_f32_16x16x32_bf16(af1, b01, acc0, 0, 0, 0);
                acc1 = __builtin_amdgcn_mfma_f32_16x16x32_bf16(af1, b11, acc1, 0, 0, 0);
                acc2 = __builtin_amdgcn_mfma_f32_16x16x32_bf16(af1, b21, acc2, 0, 0, 0);
                acc3 = __builtin_amdgcn_mfma_f32_16x16x32_bf16(af1, b31, acc3, 0, 0, 0);
                __syncthreads();
            }
            int col = n0 + fm;
            float bv0 = bias[col], bv1 = bias[col+16], bv2 = bias[col+32], bv3 = bias[col+48];
            #pragma unroll
            for (int i = 0; i < 4; i++){
                int row = m0 + wv*16 + fq*4 + i;
                if (row >= M) continue;
                int b = row/rpb, l = row - b*rpb;
                long long orow = (long long)b*1019 + ob + l;
                u16* gp = gram + orow*512;
                gp[col]      = f2bf(fmaxf(acc0[i] + bv0, 0.f));
                gp[col + 16] = f2bf(fmaxf(acc1[i] + bv1, 0.f));
                gp[col + 32] = f2bf(fmaxf(acc2[i] + bv2, 0.f));
                gp[col + 48] = f2bf(fmaxf(acc3[i] + bv3, 0.f));
            }
        } else {
            int eb = job - 512;
            int row = eb >> 3, nt = eb & 7;
            float* a   = (float*)smem;          // 768 floats
            float* red = (float*)smem + 768;    // 256 floats
            const float* A; const float* W;
            if (row < 4){ A = text + (long long)row*512*768; W = W_d; }
            else if (row < 8){ A = smax + (long long)(row-4)*768; W = W_s; }
            else { A = cmax + (long long)(row-8)*768; W = W_c; }
            for (int k = t; k < 768; k += 256) a[k] = A[k];
            __syncthreads();
            int lane = t & 63, kg = t >> 6;
            int col = nt*64 + lane;
            const float* Wp = W + (long long)(kg*192)*512 + col;
            float acc = 0.f;
            #pragma unroll 8
            for (int k = 0; k < 192; k++) acc += a[kg*192 + k] * Wp[k*512];
            red[t] = acc; __syncthreads();
            if (t < 64) emb_all[(long long)row*512 + col] = red[t] + red[t+64] + red[t+128] + red[t+192];
        }
        __syncthreads();
    }
    __threadfence(); gg.sync();

    // ================= Phase 3: W_p MFMA (512) + expmap88 (88) =================
    for (int job = bx0; job < 600; job += 256){
        if (job < 512){
            u16* As = (u16*)smem;
            u16* Bs = (u16*)(smem + 8192);
            const int K = 512, M = 4076;
            int m0 = (job >> 3) * 64;
            int n0 = (job & 7) * 64;

            int r0 = t >> 3;
            int co = (((t & 7) ^ (r0 & 7)) << 3);
            int gm0 = m0 + r0;      if (gm0 >= M) gm0 = M - 1;
            int gm1 = m0 + r0 + 32; if (gm1 >= M) gm1 = M - 1;
            const u16* a0 = gram + (long long)gm0*512 + co;
            const u16* a1 = gram + (long long)gm1*512 + co;
            const u16* bp0 = wpt + (long long)(n0 + r0)*K      + co;
            const u16* bp1 = wpt + (long long)(n0 + r0 + 32)*K + co;
            u16* lA0 = As + t*8;
            u16* lA1 = As + (256 + t)*8;
            u16* lB0 = Bs + t*8;
            u16* lB1 = Bs + (256 + t)*8;

            int lane = t & 63, wv = t >> 6;
            int fm = lane & 15, fq = lane >> 4;
            int arow = wv*16 + fm;
            int aswz = arow & 7, bswz = fm & 7;
            int aoff0 = arow*64 + ((fq     ^ aswz) << 3);
            int aoff1 = arow*64 + (((4+fq) ^ aswz) << 3);
            int boff0 = ((fq     ^ bswz) << 3);
            int boff1 = (((4+fq) ^ bswz) << 3);

            f4 acc0 = {0,0,0,0}, acc1 = {0,0,0,0}, acc2 = {0,0,0,0}, acc3 = {0,0,0,0};
            for (int k0 = 0; k0 < K; k0 += 64){
                gload16(lA0, a0 + k0);
                gload16(lA1, a1 + k0);
                gload16(lB0, bp0 + k0);
                gload16(lB1, bp1 + k0);
                __syncthreads();
                bf8 af0 = *(const bf8*)(As + aoff0);
                bf8 af1 = *(const bf8*)(As + aoff1);
                bf8 b00 = *(const bf8*)(Bs + (fm   )*64 + boff0);
                bf8 b10 = *(const bf8*)(Bs + (16+fm)*64 + boff0);
                bf8 b20 = *(const bf8*)(Bs + (32+fm)*64 + boff0);
                bf8 b30 = *(const bf8*)(Bs + (48+fm)*64 + boff0);
                bf8 b01 = *(const bf8*)(Bs + (fm   )*64 + boff1);
                bf8 b11 = *(const bf8*)(Bs + (16+fm)*64 + boff1);
                bf8 b21 = *(const bf8*)(Bs + (32+fm)*64 + boff1);
                bf8 b31 = *(const bf8*)(Bs + (48+fm)*64 + boff1);
                acc0 = __builtin_amdgcn_mfma_f32_16x16x32_bf16(af0, b00, acc0, 0, 0, 0);
                acc1 = __builtin_amdgcn_mfma_f32_16x16x32_bf16(af0, b10, acc1, 0, 0, 0);
                acc2 = __builtin_amdgcn_mfma_f32_16x16x32_bf16(af0, b20, acc2, 0, 0, 0);
                acc3 = __builtin_amdgcn_mfma_f32_16x16x32_bf16(af0, b30, acc3, 0, 0, 0);
                acc0 = __builtin_amdgcn_mfma_f32_16x16x32_bf16(af1, b01, acc0, 0, 0, 0);
                acc1 = __builtin_amdgcn_mfma_f32_16x16x32_bf16(af1, b11, acc1, 0, 0, 0);
                acc2 = __builtin_amdgcn_mfma_f32_16x16x32_bf16(af1, b21, acc2, 0, 0, 0);
                acc3 = __builtin_amdgcn_mfma_f32_16x16x32_bf16(af1, b31, acc3, 0, 0, 0);
                __syncthreads();
            }
            int col = n0 + fm;
            #pragma unroll
            for (int i = 0; i < 4; i++){
                int row = m0 + wv*16 + fq*4 + i;
                if (row >= M) continue;
                u16* dp = dwe_b + (long long)row*512;
                dp[col]      = f2bf(acc0[i]);
                dp[col + 16] = f2bf(acc1[i]);
                dp[col + 32] = f2bf(acc2[i]);
                dp[col + 48] = f2bf(acc3[i]);
            }
        } else {
            float* red = (float*)smem;
            int row = job - 512;
            float* X = emb_all + (long long)row*512;
            float2 u = *(float2*)(X + t*2);
            red[t] = u.x*u.x + u.y*u.y; __syncthreads();
            for (int s = 128; s > 0; s >>= 1){ if (t < s) red[t] += red[t+s]; __syncthreads(); }
            float f, ome;
            expmap_scale_ome(red[0], &f, &ome);
            float sx = u.x*f, sy = u.y*f;
            *(float2*)(X + t*2) = make_float2(sx, sy);
            u16* Xb = emb_b + (long long)row*512;
            Xb[t*2]   = f2bf(sx);
            Xb[t*2+1] = f2bf(sy);
            if (t == 0) ome_all[row] = ome;
        }
        __syncthreads();
    }
    __threadfence(); gg.sync();

    // ================= Phase 4: barrier-free MFMA dots (wave 0 of each block) ======
    if (t < 64){
        int b  = bx0 >> 6;          // batch 0..3
        int m0 = (bx0 & 63) * 16;   // row tile (1019 rows per batch)
        int fm = t & 15, fq = t >> 4;

        int arow = m0 + fm; if (arow > 1018) arow = 1018;   // clamp; outputs skipped
        const u16* Ap = dwe_b + ((long long)(b*1019 + arow))*512 + fq*8;

        int n1 = 16 + fm; if (n1 > 21) n1 = 21;             // clamp; outputs skipped
        int e0 = (fm == 0) ? b : (fm == 1) ? 4 + b : 8 + b*20 + (fm - 2);
        int e1 = 8 + b*20 + (n1 - 2);
        const u16* B0 = emb_b + (long long)e0*512 + fq*8;
        const u16* B1 = emb_b + (long long)e1*512 + fq*8;
        float oy0 = ome_all[e0];
        float oy1 = ome_all[e1];

        f4 acc0 = {0,0,0,0}, acc1 = {0,0,0,0};
        float ssq = 0.f;
        #pragma unroll 4
        for (int k0 = 0; k0 < 512; k0 += 32){
            bf8 av  = *(const bf8*)(Ap + k0);
            bf8 bv0 = *(const bf8*)(B0 + k0);
            bf8 bv1 = *(const bf8*)(B1 + k0);
            #pragma unroll
            for (int j = 0; j < 8; j++){ float x = bf2f(((u16*)&av)[j]); ssq += x*x; }
            acc0 = __builtin_amdgcn_mfma_f32_16x16x32_bf16(av, bv0, acc0, 0, 0, 0);
            acc1 = __builtin_amdgcn_mfma_f32_16x16x32_bf16(av, bv1, acc1, 0, 0, 0);
        }
        ssq += __shfl_xor(ssq, 16);
        ssq += __shfl_xor(ssq, 32);

        #pragma unroll
        for (int i = 0; i < 4; i++){
            int r = fq*4 + i;
            float rs = __shfl(ssq, r);
            int row = m0 + r;
            if (row >= 1019) continue;
            float f, ox;
            expmap_scale_ome(rs, &f, &ox);
            long long grow = (long long)b*1019 + row;
            {
                float s = acc0[i] * f;
                float dist = pdist_stable(ox, oy0, s);
                float inv = 1.0f/fmaxf(dist, 1e-12f);
                if (fm == 0) doc_inter[grow] = inv;
                else if (fm == 1) sum_inter[grow] = inv;
                else cand_inter[((long long)(b*20 + (fm - 2)))*1019 + row] = inv;
            }
            if (16 + fm < 22){
                float s = acc1[i] * f;
                float dist = pdist_stable(ox, oy1, s);
                float inv = 1.0f/fmaxf(dist, 1e-12f);
                cand_inter[((long long)(b*20 + (16 + fm - 2)))*1019 + row] = inv;
            }
        }
    }
    __threadfence(); gg.sync();

    // ================= Phase 5: cos_sim reductions + pair pdist =================
    if (bx0 < 84){
        float* r0 = (float*)smem;
        float* r1 = r0 + 256;
        float* r2 = r1 + 256;
        float* r3 = r2 + 256;
        int j = bx0;
        int b; const float *a, *bb; int xi, yi; int outIdx;
        if (j < 80){
            b = j/20;
            a  = doc_inter + b*1019;
            bb = cand_inter + (long long)j*1019;
            xi = 8 + j; yi = b;
            outIdx = j;
        } else {
            b = j - 80;
            a  = doc_inter + b*1019;
            bb = sum_inter + b*1019;
            xi = 4 + b; yi = b;
            outIdx = 80 + b;
        }
        const float* xe = emb_all + (long long)xi*512;
        const float* ye = emb_all + (long long)yi*512;
        float ox = ome_all[xi], oy = ome_all[yi];
        float saa = 0.f, sbb = 0.f, sab = 0.f, st = 0.f;
        for (int l = t; l < 1019; l += 256){ float av = a[l], bv = bb[l]; saa += av*av; sbb += bv*bv; sab += av*bv; }
        for (int k = t; k < 512; k += 256) st += xe[k]*ye[k];
        r0[t] = saa; r1[t] = sbb; r2[t] = sab; r3[t] = st; __syncthreads();
        for (int s = 128; s > 0; s >>= 1){
            if (t < s){ r0[t] += r0[t+s]; r1[t] += r1[t+s]; r2[t] += r2[t+s]; r3[t] += r3[t+s]; }
            __syncthreads();
        }
        if (t == 0){
            float na = fmaxf(sqrtf(r0[0]), 1e-8f);
            float nb = fmaxf(sqrtf(r1[0]), 1e-8f);
            float cosv = r2[0] / (na*nb);
            float pd = pdist_stable(ox, oy, r3[0]);
            out[outIdx] = -pd*pd + cosv;
        }
    }
}

extern "C" void kernel_launch(void* const* d_in, const int* in_sizes, int n_in,
                              void* d_out, int out_size, void* d_ws, size_t ws_size,
                              hipStream_t stream) {
    const float* text = (const float*)d_in[0];   // (4,512,768) fp32
    const float* summ = (const float*)d_in[1];   // (4,128,768)
    const float* cand = (const float*)d_in[2];   // (4,20,128,768)
    const float* W_d  = (const float*)d_in[3];   // (768,512)
    const float* W_s  = (const float*)d_in[4];
    const float* W_c  = (const float*)d_in[5];
    const float* W_p  = (const float*)d_in[6];   // (512,512)
    const float* cw1  = (const float*)d_in[7];   // (1,768,512)
    const float* cb1  = (const float*)d_in[8];   // (512,)
    const float* cw2  = (const float*)d_in[9];   // (2,768,512) = (1536,512)
    const float* cb2  = (const float*)d_in[10];  // (512,)
    float* out = (float*)d_out;                  // 84 fp32

    const int B = 4, C = 20, H = 768;

    char* base = (char*)d_ws;
    size_t off = 0;
    auto allocF = [&](size_t n)->float*{ float* p = (float*)(base + off); off += ((n*4) + 255) & ~(size_t)255; return p; };
    auto allocU = [&](size_t n)->u16*{ u16* p = (u16*)(base + off); off += ((n*2) + 255) & ~(size_t)255; return p; };

    float* smax = allocF(B*H);
    float* cmax = allocF(B*C*H);
    float* emb_all = allocF(88*512);   // 0..3 doc, 4..7 sum, 8..87 cand
    float* ome_all = allocF(88);
    u16* emb_b = allocU(88*512);       // bf16 copy of scaled embeddings
    u16* textb = allocU(4*512*768);
    u16* w1t   = allocU(512*768);
    u16* w2t   = allocU(512*1536);
    u16* wpt   = allocU(512*512);
    u16* gram  = allocU(4076*512);
    u16* dwe_b = allocU(4076*512);     // bf16 raw doc_word pre-emb
    float* doc_inter = allocF(4076);
    float* sum_inter = allocF(4076);
    float* cand_inter= allocF(B*C*1019);

    void* args[] = {
        (void*)&summ, (void*)&cand, (void*)&text,
        (void*)&cw1, (void*)&cw2, (void*)&W_p,
        (void*)&cb1, (void*)&cb2,
        (void*)&W_d, (void*)&W_s, (void*)&W_c,
        (void*)&smax, (void*)&cmax,
        (void*)&textb, (void*)&w1t, (void*)&w2t, (void*)&wpt,
        (void*)&gram, (void*)&emb_all, (void*)&ome_all, (void*)&emb_b,
        (void*)&dwe_b,
        (void*)&doc_inter, (void*)&sum_inter, (void*)&cand_inter,
        (void*)&out
    };
    hipLaunchCooperativeKernel((const void*)k_mega, dim3(256), dim3(256),
                               args, 0, stream);
}

// Round 4
// 139.668 us; speedup vs baseline: 2.9215x; 2.9215x over previous
//
#include <hip/hip_runtime.h>
#include <math.h>

#define SQRTC  0.94868329805051381f       // sqrt(0.9)
#define MAXN   (0.996f/SQRTC)             // (1-PROJ_EPS)/sqrt(c)
#define OME_CLIP (1.0f - 0.996f*0.996f)   // 1 - c*maxnorm^2
#define TWO_OVER_SQRTC 2.1081851067789197f

typedef unsigned short u16;
typedef __attribute__((ext_vector_type(8))) short bf8;   // 8 bf16 (4 VGPRs)
typedef __attribute__((ext_vector_type(4))) float f4;    // MFMA C/D

__device__ __forceinline__ u16 f2bf(float f){
    union { float f; unsigned int i; } v; v.f = f;
    unsigned int x = v.i;
    unsigned int lsb = (x >> 16) & 1u;
    x += 0x7fffu + lsb;
    return (u16)(x >> 16);
}
__device__ __forceinline__ float bf2f(u16 u){
    union { unsigned int i; float f; } v; v.i = ((unsigned int)u) << 16; return v.f;
}

// async global->LDS, 16B per lane (dest = wave-uniform base + lane*16, linear)
__device__ __forceinline__ void gload16(void* lds, const void* g){
    __builtin_amdgcn_global_load_lds(
        (const __attribute__((address_space(1))) unsigned int*)g,
        (__attribute__((address_space(3))) unsigned int*)lds,
        16, 0, 0);
}

__device__ __forceinline__ float pdist_stable(float ome_x, float ome_y, float t){
    float u = 1.0f - ome_x, v = 1.0f - ome_y;   // c*x2, c*y2
    float den = fmaxf(1.0f - 1.8f*t + u*v, 1e-15f);
    float q = ome_x*ome_y/den;                   // = 1 - z^2
    q = fminf(fmaxf(q, 2.0e-7f), 1.0f);
    float z = sqrtf(fmaxf(1.0f - q, 0.0f));
    float at = 0.5f * logf((1.0f+z)*(1.0f+z)/q); // atanh(z)
    return TWO_OVER_SQRTC * at;
}

__device__ __forceinline__ void expmap_scale_ome(float sum, float* fout, float* omeout){
    float nraw = sqrtf(fmaxf(sum, 1e-30f));
    float n = fmaxf(nraw, 1e-15f);
    float sn = SQRTC*n;
    float th = tanhf(sn);
    float factor = th/sn;
    float gn = factor*nraw;
    if (gn > MAXN){ *fout = factor*(MAXN/gn); *omeout = OME_CLIP; }
    else { *fout = factor; *omeout = fmaxf((1.0f-th)*(1.0f+th), 1e-12f); }
}

// D1: blocks 0..251 rowmax (float4); 252..1019 text cvt; 1020..2427 transposes.
__global__ __launch_bounds__(256)
void k_stage1(const float* __restrict__ summ, const float* __restrict__ cand,
              const float* __restrict__ text,
              const float* __restrict__ w1, const float* __restrict__ w2,
              const float* __restrict__ wp,
              float* __restrict__ smax, float* __restrict__ cmax,
              u16* __restrict__ textb, u16* __restrict__ w1t,
              u16* __restrict__ w2t, u16* __restrict__ wpt)
{
    __shared__ float shm[1056];
    int bx = blockIdx.x;
    int t = threadIdx.x;
    if (bx < 252){
        // rowmax over l=0..127 for one (row, 256-h chunk); float4 per lane.
        int row = bx / 3, hc = bx - row*3;
        int w = t >> 6, lane = t & 63;
        const float* in = (row < 4) ? (summ + (long long)row*128*768)
                                    : (cand + (long long)(row-4)*128*768);
        const float* p = in + (long long)(w*32)*768 + hc*256 + lane*4;
        float4 m = make_float4(-INFINITY,-INFINITY,-INFINITY,-INFINITY);
        #pragma unroll 8
        for (int l = 0; l < 32; l++){
            float4 v = *(const float4*)(p + (long long)l*768);
            m.x = fmaxf(m.x, v.x); m.y = fmaxf(m.y, v.y);
            m.z = fmaxf(m.z, v.z); m.w = fmaxf(m.w, v.w);
        }
        float4* sm4 = (float4*)shm;          // [4][64] float4 = 1024 floats
        sm4[w*64 + lane] = m; __syncthreads();
        if (t < 64){
            float4 a = sm4[t], b4 = sm4[64+t], c4 = sm4[128+t], d4 = sm4[192+t];
            float4 r;
            r.x = fmaxf(fmaxf(a.x,b4.x), fmaxf(c4.x,d4.x));
            r.y = fmaxf(fmaxf(a.y,b4.y), fmaxf(c4.y,d4.y));
            r.z = fmaxf(fmaxf(a.z,b4.z), fmaxf(c4.z,d4.z));
            r.w = fmaxf(fmaxf(a.w,b4.w), fmaxf(c4.w,d4.w));
            float* outp = (row < 4) ? (smax + row*768) : (cmax + (row-4)*768);
            *(float4*)(outp + hc*256 + t*4) = r;
        }
        return;
    }
    int pb = bx - 252;
    if (pb < 768){
        int base = pb*2048 + t*8;
        float4 a = *(const float4*)(text + base);
        float4 b = *(const float4*)(text + base + 4);
        *(ushort4*)(textb + base)     = make_ushort4(f2bf(a.x), f2bf(a.y), f2bf(a.z), f2bf(a.w));
        *(ushort4*)(textb + base + 4) = make_ushort4(f2bf(b.x), f2bf(b.y), f2bf(b.z), f2bf(b.w));
        return;
    }
    int j = pb - 768;
    const float* in; u16* outp; int K;
    if (j < 384){ in = w1; outp = w1t; K = 768; }
    else if (j < 1152){ j -= 384; in = w2; outp = w2t; K = 1536; }
    else { j -= 1152; in = wp; outp = wpt; K = 512; }
    const int N = 512, ntile = N/32;
    int k0 = (j/ntile)*32, n0 = (j - (j/ntile)*ntile)*32;
    int tx = t & 31, ty = t >> 5;
    #pragma unroll
    for (int i = 0; i < 4; i++)
        shm[(ty*4+i)*33 + tx] = in[(long long)(k0 + ty*4 + i)*N + n0 + tx];
    __syncthreads();
    #pragma unroll
    for (int i = 0; i < 4; i++)
        outp[(long long)(n0 + ty*4 + i)*K + k0 + tx] = f2bf(shm[tx*33 + ty*4+i]);
}

// D2: blocks 0..511 conv MFMA (64x64 tile, BK=64, 2-phase double-buffered
// global_load_lds prefetch w/ counted vmcnt + raw s_barrier); 512..1215 emb_gemv.
__global__ __launch_bounds__(256)
void k_stage2(const u16* __restrict__ textb,
              const u16* __restrict__ w1t, const u16* __restrict__ w2t,
              const float* __restrict__ cb1, const float* __restrict__ cb2,
              const float* __restrict__ text,
              const float* __restrict__ smax, const float* __restrict__ cmax,
              const float* __restrict__ W_d, const float* __restrict__ W_s,
              const float* __restrict__ W_c,
              u16* __restrict__ gram, float* __restrict__ emb_all)
{
    __shared__ char smem[32768];
    int bx = blockIdx.x;
    int t = threadIdx.x;
    if (bx < 512){
        u16* As0 = (u16*)smem;             // [64][64] u16, granule-XOR-swizzled
        u16* Bs0 = (u16*)(smem + 8192);
        u16* As1 = (u16*)(smem + 16384);
        u16* Bs1 = (u16*)(smem + 24576);
        int xx = bx & 63, yy = bx >> 6;
        int job = xx & 1;
        int m0 = (xx >> 1) * 64;
        int n0 = yy * 64;
        int K   = job ? 1536 : 768;
        int M   = job ? 2036 : 2040;
        int rpb = job ? 509 : 510;
        int ob  = job ? 510 : 0;
        const u16* Bt = job ? w2t : w1t;
        const float* bias = job ? cb2 : cb1;

        int r0 = t >> 3;                       // 0..31
        int co = (((t & 7) ^ (r0 & 7)) << 3);  // u16 offset within BK=64 window

        int gm0 = m0 + r0;      if (gm0 >= M) gm0 = M - 1;
        int gm1 = m0 + r0 + 32; if (gm1 >= M) gm1 = M - 1;
        int ab0 = gm0 / rpb, al0 = gm0 - ab0*rpb;
        int ab1 = gm1 / rpb, al1 = gm1 - ab1*rpb;
        const u16* a0 = textb + (long long)ab0*393216 + (long long)(al0+1)*768 + co;
        const u16* a1 = textb + (long long)ab1*393216 + (long long)(al1+1)*768 + co;
        const u16* bp0 = Bt + (long long)(n0 + r0)*K      + co;
        const u16* bp1 = Bt + (long long)(n0 + r0 + 32)*K + co;
        int d0 = t*8, d1 = (256 + t)*8;        // per-thread LDS staging offsets

        int lane = t & 63, wv = t >> 6;
        int fm = lane & 15, fq = lane >> 4;
        int arow = wv*16 + fm;
        int aswz = arow & 7, bswz = fm & 7;
        int aoff0 = arow*64 + ((fq     ^ aswz) << 3);
        int aoff1 = arow*64 + (((4+fq) ^ aswz) << 3);
        int boff0 = ((fq     ^ bswz) << 3);
        int boff1 = (((4+fq) ^ bswz) << 3);

        f4 acc0 = {0,0,0,0}, acc1 = {0,0,0,0}, acc2 = {0,0,0,0}, acc3 = {0,0,0,0};
        const int nt = K >> 6;
        // prologue: stage tile 0 into buf0
        gload16(As0 + d0, a0);
        gload16(As0 + d1, a1);
        gload16(Bs0 + d0, bp0);
        gload16(Bs0 + d1, bp1);
        for (int i = 0; i < nt; i++){
            u16* Ac = (i & 1) ? As1 : As0;
            u16* Bc = (i & 1) ? Bs1 : Bs0;
            if (i + 1 < nt){
                u16* An = (i & 1) ? As0 : As1;
                u16* Bn = (i & 1) ? Bs0 : Bs1;
                int kn = (i + 1) << 6;
                gload16(An + d0, a0 + kn);
                gload16(An + d1, a1 + kn);
                gload16(Bn + d0, bp0 + kn);
                gload16(Bn + d1, bp1 + kn);
                asm volatile("s_waitcnt vmcnt(4)" ::: "memory");  // current tile staged
            } else {
                asm volatile("s_waitcnt vmcnt(0)" ::: "memory");
            }
            __builtin_amdgcn_s_barrier();      // all waves: current tile visible
            bf8 af0 = *(const bf8*)(Ac + aoff0);
            bf8 af1 = *(const bf8*)(Ac + aoff1);
            bf8 b00 = *(const bf8*)(Bc + (fm   )*64 + boff0);
            bf8 b10 = *(const bf8*)(Bc + (16+fm)*64 + boff0);
            bf8 b20 = *(const bf8*)(Bc + (32+fm)*64 + boff0);
            bf8 b30 = *(const bf8*)(Bc + (48+fm)*64 + boff0);
            bf8 b01 = *(const bf8*)(Bc + (fm   )*64 + boff1);
            bf8 b11 = *(const bf8*)(Bc + (16+fm)*64 + boff1);
            bf8 b21 = *(const bf8*)(Bc + (32+fm)*64 + boff1);
            bf8 b31 = *(const bf8*)(Bc + (48+fm)*64 + boff1);
            acc0 = __builtin_amdgcn_mfma_f32_16x16x32_bf16(af0, b00, acc0, 0, 0, 0);
            acc1 = __builtin_amdgcn_mfma_f32_16x16x32_bf16(af0, b10, acc1, 0, 0, 0);
            acc2 = __builtin_amdgcn_mfma_f32_16x16x32_bf16(af0, b20, acc2, 0, 0, 0);
            acc3 = __builtin_amdgcn_mfma_f32_16x16x32_bf16(af0, b30, acc3, 0, 0, 0);
            acc0 = __builtin_amdgcn_mfma_f32_16x16x32_bf16(af1, b01, acc0, 0, 0, 0);
            acc1 = __builtin_amdgcn_mfma_f32_16x16x32_bf16(af1, b11, acc1, 0, 0, 0);
            acc2 = __builtin_amdgcn_mfma_f32_16x16x32_bf16(af1, b21, acc2, 0, 0, 0);
            acc3 = __builtin_amdgcn_mfma_f32_16x16x32_bf16(af1, b31, acc3, 0, 0, 0);
            __builtin_amdgcn_s_barrier();      // reads done before next prefetch overwrites
        }
        int col = n0 + fm;
        float bv0 = bias[col], bv1 = bias[col+16], bv2 = bias[col+32], bv3 = bias[col+48];
        #pragma unroll
        for (int i = 0; i < 4; i++){
            int row = m0 + wv*16 + fq*4 + i;
            if (row >= M) continue;
            int b = row/rpb, l = row - b*rpb;
            long long orow = (long long)b*1019 + ob + l;
            u16* gp = gram + orow*512;
            gp[col]      = f2bf(fmaxf(acc0[i] + bv0, 0.f));
            gp[col + 16] = f2bf(fmaxf(acc1[i] + bv1, 0.f));
            gp[col + 32] = f2bf(fmaxf(acc2[i] + bv2, 0.f));
            gp[col + 48] = f2bf(fmaxf(acc3[i] + bv3, 0.f));
        }
        return;
    }
    // ---- emb_gemv: 88 rows x 8 col-tiles ----
    {
        int eb = bx - 512;
        int row = eb >> 3, nt = eb & 7;
        float* a   = (float*)smem;          // 768 floats
        float* red = (float*)smem + 768;    // 256 floats
        const float* A; const float* W;
        if (row < 4){ A = text + (long long)row*512*768; W = W_d; }
        else if (row < 8){ A = smax + (long long)(row-4)*768; W = W_s; }
        else { A = cmax + (long long)(row-8)*768; W = W_c; }
        for (int k = t; k < 768; k += 256) a[k] = A[k];
        __syncthreads();
        int lane = t & 63, kg = t >> 6;
        int col = nt*64 + lane;
        const float* Wp = W + (long long)(kg*192)*512 + col;
        float acc = 0.f;
        #pragma unroll 8
        for (int k = 0; k < 192; k++) acc += a[kg*192 + k] * Wp[k*512];
        red[t] = acc; __syncthreads();
        if (t < 64) emb_all[(long long)row*512 + col] = red[t] + red[t+64] + red[t+128] + red[t+192];
    }
}

// D3: blocks 0..511 W_p MFMA (64x64, BK=64, 2-phase double-buffered prefetch);
// 512..599 expmap88 (+bf16 copy).
__global__ __launch_bounds__(256)
void k_stage3(const u16* __restrict__ gram, const u16* __restrict__ wpt,
              u16* __restrict__ dwe_b,
              float* __restrict__ emb_all, float* __restrict__ ome_all,
              u16* __restrict__ emb_b)
{
    __shared__ char smem[32768];
    int bx = blockIdx.x;
    int t = threadIdx.x;
    if (bx < 512){
        u16* As0 = (u16*)smem;
        u16* Bs0 = (u16*)(smem + 8192);
        u16* As1 = (u16*)(smem + 16384);
        u16* Bs1 = (u16*)(smem + 24576);
        const int K = 512, M = 4076;
        int m0 = (bx >> 3) * 64;
        int n0 = (bx & 7) * 64;

        int r0 = t >> 3;
        int co = (((t & 7) ^ (r0 & 7)) << 3);
        int gm0 = m0 + r0;      if (gm0 >= M) gm0 = M - 1;
        int gm1 = m0 + r0 + 32; if (gm1 >= M) gm1 = M - 1;
        const u16* a0 = gram + (long long)gm0*512 + co;
        const u16* a1 = gram + (long long)gm1*512 + co;
        const u16* bp0 = wpt + (long long)(n0 + r0)*K      + co;
        const u16* bp1 = wpt + (long long)(n0 + r0 + 32)*K + co;
        int d0 = t*8, d1 = (256 + t)*8;

        int lane = t & 63, wv = t >> 6;
        int fm = lane & 15, fq = lane >> 4;
        int arow = wv*16 + fm;
        int aswz = arow & 7, bswz = fm & 7;
        int aoff0 = arow*64 + ((fq     ^ aswz) << 3);
        int aoff1 = arow*64 + (((4+fq) ^ aswz) << 3);
        int boff0 = ((fq     ^ bswz) << 3);
        int boff1 = (((4+fq) ^ bswz) << 3);

        f4 acc0 = {0,0,0,0}, acc1 = {0,0,0,0}, acc2 = {0,0,0,0}, acc3 = {0,0,0,0};
        const int nt = K >> 6;   // 8
        gload16(As0 + d0, a0);
        gload16(As0 + d1, a1);
        gload16(Bs0 + d0, bp0);
        gload16(Bs0 + d1, bp1);
        for (int i = 0; i < nt; i++){
            u16* Ac = (i & 1) ? As1 : As0;
            u16* Bc = (i & 1) ? Bs1 : Bs0;
            if (i + 1 < nt){
                u16* An = (i & 1) ? As0 : As1;
                u16* Bn = (i & 1) ? Bs0 : Bs1;
                int kn = (i + 1) << 6;
                gload16(An + d0, a0 + kn);
                gload16(An + d1, a1 + kn);
                gload16(Bn + d0, bp0 + kn);
                gload16(Bn + d1, bp1 + kn);
                asm volatile("s_waitcnt vmcnt(4)" ::: "memory");
            } else {
                asm volatile("s_waitcnt vmcnt(0)" ::: "memory");
            }
            __builtin_amdgcn_s_barrier();
            bf8 af0 = *(const bf8*)(Ac + aoff0);
            bf8 af1 = *(const bf8*)(Ac + aoff1);
            bf8 b00 = *(const bf8*)(Bc + (fm   )*64 + boff0);
            bf8 b10 = *(const bf8*)(Bc + (16+fm)*64 + boff0);
            bf8 b20 = *(const bf8*)(Bc + (32+fm)*64 + boff0);
            bf8 b30 = *(const bf8*)(Bc + (48+fm)*64 + boff0);
            bf8 b01 = *(const bf8*)(Bc + (fm   )*64 + boff1);
            bf8 b11 = *(const bf8*)(Bc + (16+fm)*64 + boff1);
            bf8 b21 = *(const bf8*)(Bc + (32+fm)*64 + boff1);
            bf8 b31 = *(const bf8*)(Bc + (48+fm)*64 + boff1);
            acc0 = __builtin_amdgcn_mfma_f32_16x16x32_bf16(af0, b00, acc0, 0, 0, 0);
            acc1 = __builtin_amdgcn_mfma_f32_16x16x32_bf16(af0, b10, acc1, 0, 0, 0);
            acc2 = __builtin_amdgcn_mfma_f32_16x16x32_bf16(af0, b20, acc2, 0, 0, 0);
            acc3 = __builtin_amdgcn_mfma_f32_16x16x32_bf16(af0, b30, acc3, 0, 0, 0);
            acc0 = __builtin_amdgcn_mfma_f32_16x16x32_bf16(af1, b01, acc0, 0, 0, 0);
            acc1 = __builtin_amdgcn_mfma_f32_16x16x32_bf16(af1, b11, acc1, 0, 0, 0);
            acc2 = __builtin_amdgcn_mfma_f32_16x16x32_bf16(af1, b21, acc2, 0, 0, 0);
            acc3 = __builtin_amdgcn_mfma_f32_16x16x32_bf16(af1, b31, acc3, 0, 0, 0);
            __builtin_amdgcn_s_barrier();
        }
        int col = n0 + fm;
        #pragma unroll
        for (int i = 0; i < 4; i++){
            int row = m0 + wv*16 + fq*4 + i;
            if (row >= M) continue;
            u16* dp = dwe_b + (long long)row*512;
            dp[col]      = f2bf(acc0[i]);
            dp[col + 16] = f2bf(acc1[i]);
            dp[col + 32] = f2bf(acc2[i]);
            dp[col + 48] = f2bf(acc3[i]);
        }
        return;
    }
    // ---- expmap0 in-place on the 88 emb rows; also emit bf16 copy ----
    {
        float* red = (float*)smem;
        int row = bx - 512;
        float* X = emb_all + (long long)row*512;
        float2 u = *(float2*)(X + t*2);
        red[t] = u.x*u.x + u.y*u.y; __syncthreads();
        for (int s = 128; s > 0; s >>= 1){ if (t < s) red[t] += red[t+s]; __syncthreads(); }
        float f, ome;
        expmap_scale_ome(red[0], &f, &ome);
        float sx = u.x*f, sy = u.y*f;
        *(float2*)(X + t*2) = make_float2(sx, sy);
        u16* Xb = emb_b + (long long)row*512;
        Xb[t*2]   = f2bf(sx);
        Xb[t*2+1] = f2bf(sy);
        if (t == 0) ome_all[row] = ome;
    }
}

// D4: barrier-free MFMA dots. 256 blocks x 1 wave; each wave owns 16 rows x 22 cols.
// A-frag and B-frag are loaded DIRECTLY from row-major global (16B contiguous per
// lane, L2-resident) -- no LDS, no __syncthreads in the K-loop. ssq per row via
// 2x shfl_xor; epilogue = expmap scale + pdist.
__global__ __launch_bounds__(64)
void k_dots_mfma(const u16* __restrict__ dwe_b, const u16* __restrict__ emb_b,
                 const float* __restrict__ ome_all,
                 float* __restrict__ doc_inter, float* __restrict__ sum_inter,
                 float* __restrict__ cand_inter)
{
    int bx = blockIdx.x;
    int b  = bx >> 6;           // batch 0..3
    int m0 = (bx & 63) * 16;    // row tile (1019 rows per batch)
    int t = threadIdx.x;        // lane 0..63
    int fm = t & 15, fq = t >> 4;

    int arow = m0 + fm; if (arow > 1018) arow = 1018;   // clamp; outputs skipped
    const u16* Ap = dwe_b + ((long long)(b*1019 + arow))*512 + fq*8;

    int n1 = 16 + fm; if (n1 > 21) n1 = 21;             // clamp; outputs skipped
    int e0 = (fm == 0) ? b : (fm == 1) ? 4 + b : 8 + b*20 + (fm - 2);
    int e1 = 8 + b*20 + (n1 - 2);
    const u16* B0 = emb_b + (long long)e0*512 + fq*8;
    const u16* B1 = emb_b + (long long)e1*512 + fq*8;
    float oy0 = ome_all[e0];
    float oy1 = ome_all[e1];

    f4 acc0 = {0,0,0,0}, acc1 = {0,0,0,0};
    float ssq = 0.f;
    #pragma unroll 4
    for (int k0 = 0; k0 < 512; k0 += 32){
        bf8 av  = *(const bf8*)(Ap + k0);
        bf8 bv0 = *(const bf8*)(B0 + k0);
        bf8 bv1 = *(const bf8*)(B1 + k0);
        #pragma unroll
        for (int j = 0; j < 8; j++){ float x = bf2f(((u16*)&av)[j]); ssq += x*x; }
        acc0 = __builtin_amdgcn_mfma_f32_16x16x32_bf16(av, bv0, acc0, 0, 0, 0);
        acc1 = __builtin_amdgcn_mfma_f32_16x16x32_bf16(av, bv1, acc1, 0, 0, 0);
    }
    // row-sum of squares: lanes {fm, fm+16, fm+32, fm+48} hold complementary K-slices
    ssq += __shfl_xor(ssq, 16);
    ssq += __shfl_xor(ssq, 32);
    // now every lane holds rowsum for row index == its fm

    #pragma unroll
    for (int i = 0; i < 4; i++){
        int r = fq*4 + i;                 // C/D row within 16-tile for this lane
        float rs = __shfl(ssq, r);        // uniform control: all lanes participate
        int row = m0 + r;
        if (row >= 1019) continue;
        float f, ox;
        expmap_scale_ome(rs, &f, &ox);
        long long grow = (long long)b*1019 + row;
        // c = fm (acc0) and 16+fm (acc1)
        {
            float s = acc0[i] * f;
            float dist = pdist_stable(ox, oy0, s);
            float inv = 1.0f/fmaxf(dist, 1e-12f);
            if (fm == 0) doc_inter[grow] = inv;
            else if (fm == 1) sum_inter[grow] = inv;
            else cand_inter[((long long)(b*20 + (fm - 2)))*1019 + row] = inv;
        }
        if (16 + fm < 22){
            float s = acc1[i] * f;
            float dist = pdist_stable(ox, oy1, s);
            float inv = 1.0f/fmaxf(dist, 1e-12f);
            cand_inter[((long long)(b*20 + (16 + fm - 2)))*1019 + row] = inv;
        }
    }
}

// D5: blocks 0..79 -> score[b,c]; 80..83 -> summary_score[b]; fp32 out
__global__ __launch_bounds__(256)
void k_final(const float* __restrict__ doc_inter, const float* __restrict__ sum_inter,
             const float* __restrict__ cand_inter,
             const float* __restrict__ emb_all, const float* __restrict__ ome_all,
             float* __restrict__ out)
{
    __shared__ float r0[256], r1[256], r2[256], r3[256];
    int j = blockIdx.x, t = threadIdx.x;
    int b; const float *a, *bb; int xi, yi; int outIdx;
    if (j < 80){
        b = j/20;
        a  = doc_inter + b*1019;
        bb = cand_inter + (long long)j*1019;
        xi = 8 + j; yi = b;
        outIdx = j;
    } else {
        b = j - 80;
        a  = doc_inter + b*1019;
        bb = sum_inter + b*1019;
        xi = 4 + b; yi = b;
        outIdx = 80 + b;
    }
    const float* xe = emb_all + (long long)xi*512;
    const float* ye = emb_all + (long long)yi*512;
    float ox = ome_all[xi], oy = ome_all[yi];
    float saa = 0.f, sbb = 0.f, sab = 0.f, st = 0.f;
    for (int l = t; l < 1019; l += 256){ float av = a[l], bv = bb[l]; saa += av*av; sbb += bv*bv; sab += av*bv; }
    for (int k = t; k < 512; k += 256) st += xe[k]*ye[k];
    r0[t] = saa; r1[t] = sbb; r2[t] = sab; r3[t] = st; __syncthreads();
    for (int s = 128; s > 0; s >>= 1){
        if (t < s){ r0[t] += r0[t+s]; r1[t] += r1[t+s]; r2[t] += r2[t+s]; r3[t] += r3[t+s]; }
        __syncthreads();
    }
    if (t == 0){
        float na = fmaxf(sqrtf(r0[0]), 1e-8f);
        float nb = fmaxf(sqrtf(r1[0]), 1e-8f);
        float cosv = r2[0] / (na*nb);
        float pd = pdist_stable(ox, oy, r3[0]);
        out[outIdx] = -pd*pd + cosv;
    }
}

extern "C" void kernel_launch(void* const* d_in, const int* in_sizes, int n_in,
                              void* d_out, int out_size, void* d_ws, size_t ws_size,
                              hipStream_t stream) {
    const float* text = (const float*)d_in[0];   // (4,512,768) fp32
    const float* summ = (const float*)d_in[1];   // (4,128,768)
    const float* cand = (const float*)d_in[2];   // (4,20,128,768)
    const float* W_d  = (const float*)d_in[3];   // (768,512)
    const float* W_s  = (const float*)d_in[4];
    const float* W_c  = (const float*)d_in[5];
    const float* W_p  = (const float*)d_in[6];   // (512,512)
    const float* cw1  = (const float*)d_in[7];   // (1,768,512)
    const float* cb1  = (const float*)d_in[8];   // (512,)
    const float* cw2  = (const float*)d_in[9];   // (2,768,512) = (1536,512)
    const float* cb2  = (const float*)d_in[10];  // (512,)
    float* out = (float*)d_out;                  // 84 fp32

    const int B = 4, C = 20, H = 768;

    char* base = (char*)d_ws;
    size_t off = 0;
    auto allocF = [&](size_t n)->float*{ float* p = (float*)(base + off); off += ((n*4) + 255) & ~(size_t)255; return p; };
    auto allocU = [&](size_t n)->u16*{ u16* p = (u16*)(base + off); off += ((n*2) + 255) & ~(size_t)255; return p; };

    float* smax = allocF(B*H);
    float* cmax = allocF(B*C*H);
    float* emb_all = allocF(88*512);   // 0..3 doc, 4..7 sum, 8..87 cand
    float* ome_all = allocF(88);
    u16* emb_b = allocU(88*512);       // bf16 copy of scaled embeddings
    u16* textb = allocU(4*512*768);
    u16* w1t   = allocU(512*768);
    u16* w2t   = allocU(512*1536);
    u16* wpt   = allocU(512*512);
    u16* gram  = allocU(4076*512);
    u16* dwe_b = allocU(4076*512);     // bf16 raw doc_word pre-emb
    float* doc_inter = allocF(4076);
    float* sum_inter = allocF(4076);
    float* cand_inter= allocF(B*C*1019);

    // D1: rowmax (float4) + prep (independent jobs)
    k_stage1<<<2428, 256, 0, stream>>>(summ, cand, text, cw1, cw2, W_p,
                                       smax, cmax, textb, w1t, w2t, wpt);

    // D2: conv MFMA (64x64, BK=64, 2-phase prefetch) + emb_gemv
    k_stage2<<<1216, 256, 0, stream>>>(textb, w1t, w2t, cb1, cb2,
                                       text, smax, cmax, W_d, W_s, W_c,
                                       gram, emb_all);

    // D3: W_p MFMA (64x64, BK=64, 2-phase prefetch) + expmap88/bf16-copy
    k_stage3<<<600, 256, 0, stream>>>(gram, wpt, dwe_b, emb_all, ome_all, emb_b);

    // D4: barrier-free MFMA dots, 1 wave per 16-row tile
    k_dots_mfma<<<256, 64, 0, stream>>>(dwe_b, emb_b, ome_all,
                                        doc_inter, sum_inter, cand_inter);

    // D5: cos_sim reductions + pair pdist -> fp32 outputs
    k_final<<<84, 256, 0, stream>>>(doc_inter, sum_inter, cand_inter,
                                    emb_all, ome_all, out);
}